// Round 16
// baseline (2785.060 us; speedup 1.0000x reference)
//
#include <hip/hip_runtime.h>
#include <cmath>

#define B_ 8
#define Q_ 100
#define D_ 256
#define H_ 8
#define HD_ 32
#define L_ 9
#define F_ 2048
#define C_ 151
#define HM_ 112
#define PMAX_ 3136
#define KT_ 128
#define RECSZ 544   // 16 m + 16 l + 16*32 O
#define PMS 116     // LDS plane stride (mult of 4, good bank spread)

typedef __attribute__((ext_vector_type(4))) short s4v;
typedef __attribute__((ext_vector_type(8))) short s8v;
typedef __attribute__((ext_vector_type(4))) float f4v;

__device__ __forceinline__ unsigned short f2bf(float x) {
  unsigned int u = __float_as_uint(x);
  return (unsigned short)((u + 0x7fffu + ((u >> 16) & 1u)) >> 16);
}
__device__ __forceinline__ float bf2f(unsigned short h) {
  return __uint_as_float(((unsigned int)h) << 16);
}
__device__ __forceinline__ void split2(float x, short& h, short& l) {
  unsigned short hb = f2bf(x);
  float r = x - bf2f(hb);
  h = (short)hb;
  l = (short)f2bf(r);
}

__device__ __forceinline__ float block_sum(float v, float* red) {
  int t = threadIdx.x;
  red[t] = v; __syncthreads();
  for (int s = 128; s > 0; s >>= 1) {
    if (t < s) red[t] += red[t + s];
    __syncthreads();
  }
  float r = red[0]; __syncthreads();
  return r;
}

// ---------------- init q ----------------
__global__ __launch_bounds__(256) void initq_kernel(const float* __restrict__ qf,
                                                    const float* __restrict__ qe,
                                                    float* __restrict__ q) {
  int idx = blockIdx.x * 256 + threadIdx.x;
  int qd = idx % (Q_ * D_);
  q[idx] = qf[qd] + qe[qd];
}

// ---------------- per-channel antialias resize (wave-cooperative taps) ----------------
// Each output handled by a TAPS-wide lane group: lane xi owns x-tap xi, loops y-taps,
// then shfl_xor tree reduce (group-aligned). Conflict-free LDS reads.
template <int OH>
__device__ __forceinline__ void resize_coop(const float* __restrict__ pm,
                                            float* __restrict__ out,
                                            float* wbuf, int* sbuf, int t) {
  constexpr int RATIO = HM_ / OH;
  constexpr int TAPS = 2 * RATIO;
  constexpr int GPB = 256 / TAPS;          // groups (outputs) per iteration
  constexpr float INVR = 1.f / (float)RATIO;
  if (t < OH) {
    float s = ((float)t + 0.5f) * RATIO - 0.5f;
    int x0 = (int)floorf(s - RATIO) + 1;
    sbuf[t] = x0;
    float ws = 0.f;
#pragma unroll
    for (int si = 0; si < TAPS; ++si) {
      int x = x0 + si;
      float w = (x >= 0 && x < HM_) ? 1.f - fabsf(s - (float)x) * INVR : 0.f;
      wbuf[t * TAPS + si] = w;
      ws += w;
    }
    float inv = 1.f / ws;
#pragma unroll
    for (int si = 0; si < TAPS; ++si) wbuf[t * TAPS + si] *= inv;
  }
  __syncthreads();
  const int xi = t & (TAPS - 1);
  const int g = t >> (31 - __builtin_clz(TAPS));   // t / TAPS (TAPS pow2)
  for (int p0 = 0; p0 < OH * OH; p0 += GPB) {
    int p = p0 + g;
    float acc = 0.f;
    if (p < OH * OH) {
      int oy = p / OH, ox = p - oy * OH;
      int x0 = sbuf[ox], y0 = sbuf[oy];
      const float* wy = &wbuf[oy * TAPS];
      int x = min(max(x0 + xi, 0), HM_ - 1);
      const float* px = pm + x;
#pragma unroll
      for (int ti = 0; ti < TAPS; ++ti) {
        int y = min(max(y0 + ti, 0), HM_ - 1);
        acc += wy[ti] * px[y * PMS];
      }
      acc *= wbuf[ox * TAPS + xi];
    }
#pragma unroll
    for (int off = TAPS / 2; off > 0; off >>= 1) acc += __shfl_xor(acc, off, 64);
    if (p < OH * OH && xi == 0) out[p] = acc;
  }
  __syncthreads();
}

__global__ __launch_bounds__(256) void resize3_kernel(
    const float* __restrict__ mf, float* __restrict__ r0,
    float* __restrict__ r1, float* __restrict__ r2) {
  __shared__ float pm[HM_ * PMS];
  __shared__ float wbuf[224];
  __shared__ int sbuf[56];
  const int bd = blockIdx.x;
  const float* pl = mf + (size_t)bd * (HM_ * HM_);
  const int t = threadIdx.x;
  for (int f = t; f < (HM_ * HM_) / 4; f += 256) {
    int row = f / 28, c = (f - row * 28) * 4;
    *(f4v*)&pm[row * PMS + c] = ((const f4v*)pl)[f];
  }
  __syncthreads();
  resize_coop<14>(pm, r0 + (size_t)bd * 196, wbuf, sbuf, t);
  resize_coop<28>(pm, r1 + (size_t)bd * 784, wbuf, sbuf, t);
  resize_coop<56>(pm, r2 + (size_t)bd * 3136, wbuf, sbuf, t);
}

// ---------------- transpose-split: fp32 [K][N] -> bf16 [N][2K] ----------------
__global__ __launch_bounds__(256) void tsplit_kernel(
    const float* __restrict__ in, short* __restrict__ out,
    int K, int N, long long ibs, long long obs) {
  __shared__ float tile[32][33];
  const int z = blockIdx.z;
  const int nb = blockIdx.x * 32, kb = blockIdx.y * 32;
  const float* I = in + (size_t)z * ibs;
  short* O = out + (size_t)z * obs;
  const int t = threadIdx.x;
  {
    const int r = t >> 3, c = (t & 7) * 4;
    const int gk = kb + r;
#pragma unroll
    for (int j = 0; j < 4; ++j) {
      int gn = nb + c + j;
      tile[r][c + j] = (gk < K && gn < N) ? I[(size_t)gk * N + gn] : 0.f;
    }
  }
  __syncthreads();
  {
    const int nr = t >> 3, kc = (t & 7) * 4;
    const int gn = nb + nr;
    if (gn < N) {
#pragma unroll
      for (int j = 0; j < 4; ++j) {
        int gk = kb + kc + j;
        if (gk < K) {
          short h, l; split2(tile[kc + j][nr], h, l);
          O[(size_t)gn * 2 * K + gk] = h;
          O[(size_t)gn * 2 * K + K + gk] = l;
        }
      }
    }
  }
}

// ---------------- transpose-split with zero pad: N real -> Na alloc ----------------
__global__ __launch_bounds__(256) void tsplitp_kernel(
    const float* __restrict__ in, short* __restrict__ out,
    int K, int N, int Na, long long ibs, long long obs) {
  __shared__ float tile[32][33];
  const int z = blockIdx.z;
  const int nb = blockIdx.x * 32, kb = blockIdx.y * 32;
  const float* I = in + (size_t)z * ibs;
  short* O = out + (size_t)z * obs;
  const int t = threadIdx.x;
  {
    const int r = t >> 3, c = (t & 7) * 4;
    const int gk = kb + r;
#pragma unroll
    for (int j = 0; j < 4; ++j) {
      int gn = nb + c + j;
      tile[r][c + j] = (gk < K && gn < N) ? I[(size_t)gk * N + gn] : 0.f;
    }
  }
  __syncthreads();
  {
    const int nr = t >> 3, kc = (t & 7) * 4;
    const int gn = nb + nr;
    if (gn < Na) {
#pragma unroll
      for (int j = 0; j < 4; ++j) {
        int gk = kb + kc + j;
        if (gk < K) {
          short h, l; split2(tile[kc + j][nr], h, l);
          O[(size_t)gn * 2 * K + gk] = h;
          O[(size_t)gn * 2 * K + K + gk] = l;
        }
      }
    }
  }
}

// ---------------- MFMA frag load ----------------
__device__ __forceinline__ s8v ldfrag(const short* p) {
  s4v lo = *(const s4v*)p;
  s4v hi = *(const s4v*)(p + 16);
  return __builtin_shufflevector(lo, hi, 0, 1, 2, 3, 4, 5, 6, 7);
}

// ---------------- MFMA bf16x3 GEMM ----------------
template <int BM, int AMODE, int WMODE, bool RELU, int OUT>
__global__ __launch_bounds__(256) void mgemm_kernel(
    const void* __restrict__ Ap, const void* __restrict__ Wp,
    const float* __restrict__ bias, void* __restrict__ Cv,
    int M, int N, int K,
    long long Abs, long long Wbs, long long Cbs, int ldc, int swap) {
  constexpr int MI = BM / 32;
  __shared__ short Ah[BM * 36], Al[BM * 36], Wh[128 * 36], Wl[128 * 36];
  const int z = blockIdx.z;
  const int bx = swap ? blockIdx.y : blockIdx.x;
  const int by = swap ? blockIdx.x : blockIdx.y;
  const int n0 = bx * 128, m0 = by * BM;
  const int t = threadIdx.x;
  const int lane = t & 63;
  const int wave = t >> 6;
  const int wm = wave >> 1, wn = wave & 1;
  const int lr = lane & 15, lg = lane >> 4;
  f4v acc[MI][4];
#pragma unroll
  for (int i = 0; i < MI; ++i)
#pragma unroll
    for (int j = 0; j < 4; ++j) acc[i][j] = (f4v){0.f, 0.f, 0.f, 0.f};

  for (int k0 = 0; k0 < K; k0 += 32) {
    if (AMODE == 0) {
      const float* A = (const float*)Ap + (size_t)z * Abs;
      if (BM == 64) {
        const int arow = t >> 2;
        const int kc = (t & 3) * 8;
        float x[8];
        if (m0 + arow < M) {
          const float* ap = A + (size_t)(m0 + arow) * K + k0 + kc;
          *(f4v*)&x[0] = *(const f4v*)ap;
          *(f4v*)&x[4] = *(const f4v*)(ap + 4);
        } else {
#pragma unroll
          for (int e = 0; e < 8; ++e) x[e] = 0.f;
        }
        s4v h0, h1, l0, l1;
#pragma unroll
        for (int e = 0; e < 4; ++e) { short hh, ll; split2(x[e], hh, ll); h0[e] = hh; l0[e] = ll; }
#pragma unroll
        for (int e = 0; e < 4; ++e) { short hh, ll; split2(x[4 + e], hh, ll); h1[e] = hh; l1[e] = ll; }
        *(s4v*)&Ah[arow * 36 + kc] = h0; *(s4v*)&Ah[arow * 36 + kc + 4] = h1;
        *(s4v*)&Al[arow * 36 + kc] = l0; *(s4v*)&Al[arow * 36 + kc + 4] = l1;
      } else {
        const int arow = t >> 3;
        const int kc = (t & 7) * 4;
        float x[4];
        if (m0 + arow < M) {
          *(f4v*)&x[0] = *(const f4v*)(A + (size_t)(m0 + arow) * K + k0 + kc);
        } else {
#pragma unroll
          for (int e = 0; e < 4; ++e) x[e] = 0.f;
        }
        s4v h0, l0;
#pragma unroll
        for (int e = 0; e < 4; ++e) { short hh, ll; split2(x[e], hh, ll); h0[e] = hh; l0[e] = ll; }
        *(s4v*)&Ah[arow * 36 + kc] = h0;
        *(s4v*)&Al[arow * 36 + kc] = l0;
      }
    } else {
      const short* A2 = (const short*)Ap + (size_t)z * Abs;
      const int arow = t >> 2;
      const int c = t & 3, sel = c >> 1, ko = (c & 1) * 16;
      s8v v0 = {0, 0, 0, 0, 0, 0, 0, 0}, v1 = {0, 0, 0, 0, 0, 0, 0, 0};
      if (m0 + arow < M) {
        const short* ap = A2 + (size_t)(m0 + arow) * (2 * K) + sel * K + k0 + ko;
        v0 = *(const s8v*)ap;
        v1 = *(const s8v*)(ap + 8);
      }
      short* dst = sel ? Al : Ah;
      *(s4v*)&dst[arow * 36 + ko] = __builtin_shufflevector(v0, v0, 0, 1, 2, 3);
      *(s4v*)&dst[arow * 36 + ko + 4] = __builtin_shufflevector(v0, v0, 4, 5, 6, 7);
      *(s4v*)&dst[arow * 36 + ko + 8] = __builtin_shufflevector(v1, v1, 0, 1, 2, 3);
      *(s4v*)&dst[arow * 36 + ko + 12] = __builtin_shufflevector(v1, v1, 4, 5, 6, 7);
    }
    if (WMODE == 0) {
      const short* W2 = (const short*)Wp + (size_t)z * Wbs;
      const int n = t >> 1, sel = t & 1;
      const short* wp = W2 + (size_t)(n0 + n) * (2 * K) + sel * K + k0;
      short* dst = sel ? Wl : Wh;
#pragma unroll
      for (int j = 0; j < 4; ++j) {
        s8v v = *(const s8v*)(wp + j * 8);
        *(s4v*)&dst[n * 36 + j * 8] = __builtin_shufflevector(v, v, 0, 1, 2, 3);
        *(s4v*)&dst[n * 36 + j * 8 + 4] = __builtin_shufflevector(v, v, 4, 5, 6, 7);
      }
    } else {
      const float* W = (const float*)Wp + (size_t)z * Wbs;
      const int kr = t >> 3, c0 = (t & 7) * 16;
      const float* wp = W + (size_t)(k0 + kr) * N + n0 + c0;
      float x[16];
#pragma unroll
      for (int j = 0; j < 4; ++j) *(f4v*)&x[j * 4] = *(const f4v*)(wp + j * 4);
#pragma unroll
      for (int j = 0; j < 16; ++j) {
        short hh, ll; split2(x[j], hh, ll);
        Wh[(c0 + j) * 36 + kr] = hh;
        Wl[(c0 + j) * 36 + kr] = ll;
      }
    }
    __syncthreads();
    s8v whf[4], wlf[4];
#pragma unroll
    for (int ni = 0; ni < 4; ++ni) {
      whf[ni] = ldfrag(&Wh[(wn * 64 + ni * 16 + lr) * 36 + 4 * lg]);
      wlf[ni] = ldfrag(&Wl[(wn * 64 + ni * 16 + lr) * 36 + 4 * lg]);
    }
#pragma unroll
    for (int mi = 0; mi < MI; ++mi) {
      s8v ah = ldfrag(&Ah[(wm * (BM / 2) + mi * 16 + lr) * 36 + 4 * lg]);
      s8v al = ldfrag(&Al[(wm * (BM / 2) + mi * 16 + lr) * 36 + 4 * lg]);
#pragma unroll
      for (int ni = 0; ni < 4; ++ni) {
        acc[mi][ni] = __builtin_amdgcn_mfma_f32_16x16x32_bf16(ah, whf[ni], acc[mi][ni], 0, 0, 0);
        acc[mi][ni] = __builtin_amdgcn_mfma_f32_16x16x32_bf16(al, whf[ni], acc[mi][ni], 0, 0, 0);
        acc[mi][ni] = __builtin_amdgcn_mfma_f32_16x16x32_bf16(ah, wlf[ni], acc[mi][ni], 0, 0, 0);
      }
    }
    __syncthreads();
  }
  float* Cf = (float*)Cv + (size_t)z * Cbs;
  unsigned short* Ch = (unsigned short*)Cv + (size_t)z * Cbs;
#pragma unroll
  for (int mi = 0; mi < MI; ++mi) {
#pragma unroll
    for (int i = 0; i < 4; ++i) {
      int row = m0 + wm * (BM / 2) + mi * 16 + 4 * lg + i;
      if (row >= M) continue;
#pragma unroll
      for (int ni = 0; ni < 4; ++ni) {
        int col = n0 + wn * 64 + ni * 16 + lr;
        float v = acc[mi][ni][i] + (bias ? bias[col] : 0.f);
        if (RELU) v = fmaxf(v, 0.f);
        if (OUT == 0) Cf[(size_t)row * ldc + col] = v;
        else Ch[(size_t)row * ldc + col] = f2bf(v);
      }
    }
  }
}

// ---------------- fused mask head: dec_ln + me1 + me2 + me3 ----------------
__global__ __launch_bounds__(256) void maskhead_kernel(
    const float* __restrict__ q, const float* __restrict__ lns,
    const float* __restrict__ lnb, const short* __restrict__ W123,
    const float* __restrict__ b1, const float* __restrict__ b2,
    const float* __restrict__ b3,
    float* __restrict__ nqout, float* __restrict__ me3out) {
  __shared__ float Xb[16 * 264], Yb[16 * 264];
  __shared__ short Ah[16 * 36], Al[16 * 36], Wh[256 * 36], Wl[256 * 36];
  const int r0 = blockIdx.x * 16;
  const int t = threadIdx.x;
  const int lane = t & 63, w = t >> 6;
  const int lr = lane & 15, lg = lane >> 4;
#pragma unroll
  for (int rr = 0; rr < 4; ++rr) {
    int row = w * 4 + rr;
    int grow = r0 + row;
    f4v v = *((const f4v*)(q + (size_t)grow * D_) + lane);
    float sum = v[0] + v[1] + v[2] + v[3];
#pragma unroll
    for (int off = 32; off > 0; off >>= 1) sum += __shfl_xor(sum, off, 64);
    float mean = sum * (1.f / D_);
    float c0 = v[0] - mean, c1 = v[1] - mean, c2 = v[2] - mean, c3 = v[3] - mean;
    float vs = c0 * c0 + c1 * c1 + c2 * c2 + c3 * c3;
#pragma unroll
    for (int off = 32; off > 0; off >>= 1) vs += __shfl_xor(vs, off, 64);
    float inv = rsqrtf(vs * (1.f / D_) + 1e-5f);
    f4v sv = *((const f4v*)lns + lane);
    f4v bv = *((const f4v*)lnb + lane);
    f4v o;
    o[0] = c0 * inv * sv[0] + bv[0];
    o[1] = c1 * inv * sv[1] + bv[1];
    o[2] = c2 * inv * sv[2] + bv[2];
    o[3] = c3 * inv * sv[3] + bv[3];
    *(f4v*)&Xb[row * 264 + lane * 4] = o;
    *((f4v*)(nqout + (size_t)grow * D_) + lane) = o;
  }
  __syncthreads();
  float* src = Xb;
  float* dst = Yb;
  for (int s = 0; s < 3; ++s) {
    const short* Ws = W123 + (size_t)s * 131072;
    const float* bs = (s == 0) ? b1 : ((s == 1) ? b2 : b3);
    f4v acc[4];
#pragma unroll
    for (int j = 0; j < 4; ++j) acc[j] = (f4v){0.f, 0.f, 0.f, 0.f};
    for (int k0 = 0; k0 < 256; k0 += 32) {
      {
        int idx = t * 2;
        int row = idx >> 5, kc = idx & 31;
        short h0, l0, h1, l1;
        split2(src[row * 264 + k0 + kc], h0, l0);
        split2(src[row * 264 + k0 + kc + 1], h1, l1);
        Ah[row * 36 + kc] = h0; Ah[row * 36 + kc + 1] = h1;
        Al[row * 36 + kc] = l0; Al[row * 36 + kc + 1] = l1;
      }
      {
        const short* wp = Ws + (size_t)t * 512 + k0;
#pragma unroll
        for (int j = 0; j < 8; ++j)
          *(s4v*)&Wh[t * 36 + j * 4] = *(const s4v*)(wp + j * 4);
        const short* wpl = wp + 256;
#pragma unroll
        for (int j = 0; j < 8; ++j)
          *(s4v*)&Wl[t * 36 + j * 4] = *(const s4v*)(wpl + j * 4);
      }
      __syncthreads();
      s8v ah = ldfrag(&Ah[lr * 36 + 4 * lg]);
      s8v al = ldfrag(&Al[lr * 36 + 4 * lg]);
#pragma unroll
      for (int ni = 0; ni < 4; ++ni) {
        s8v wh = ldfrag(&Wh[(w * 64 + ni * 16 + lr) * 36 + 4 * lg]);
        s8v wl = ldfrag(&Wl[(w * 64 + ni * 16 + lr) * 36 + 4 * lg]);
        acc[ni] = __builtin_amdgcn_mfma_f32_16x16x32_bf16(ah, wh, acc[ni], 0, 0, 0);
        acc[ni] = __builtin_amdgcn_mfma_f32_16x16x32_bf16(al, wh, acc[ni], 0, 0, 0);
        acc[ni] = __builtin_amdgcn_mfma_f32_16x16x32_bf16(ah, wl, acc[ni], 0, 0, 0);
      }
      __syncthreads();
    }
#pragma unroll
    for (int ni = 0; ni < 4; ++ni) {
#pragma unroll
      for (int i = 0; i < 4; ++i) {
        int row = 4 * lg + i;
        int col = w * 64 + ni * 16 + lr;
        float v = acc[ni][i] + bs[col];
        if (s < 2) v = fmaxf(v, 0.f);
        dst[row * 264 + col] = v;
      }
    }
    __syncthreads();
    float* tmpp = src; src = dst; dst = tmpp;
  }
  for (int o = t; o < 16 * 256; o += 256) {
    int row = o >> 8, col = o & 255;
    me3out[(size_t)(r0 + row) * D_ + col] = src[row * 264 + col];
  }
}

// ---------------- fp32 GEMM (cls head only) ----------------
__global__ __launch_bounds__(256) void gemm32_kernel(
    const float* __restrict__ A, const float* __restrict__ W,
    const float* __restrict__ bias, float* __restrict__ C,
    int M, int N, int K) {
  __shared__ float As[16][65];
  __shared__ float Ws[16][65];
  const int n0 = blockIdx.x * 64, m0 = blockIdx.y * 64;
  const int t = threadIdx.x;
  const int tm = t >> 4, tn = t & 15;
  float acc[4][4] = {};
  for (int k0 = 0; k0 < K; k0 += 16) {
#pragma unroll
    for (int l = 0; l < 4; ++l) {
      int idx = t + l * 256;
      int am = idx >> 4, ak = idx & 15;
      int gm = m0 + am, gk = k0 + ak;
      As[ak][am] = (gm < M) ? A[(size_t)gm * K + gk] : 0.f;
      int wk = idx >> 6, wn = idx & 63;
      int gn = n0 + wn, gk2 = k0 + wk;
      Ws[wk][wn] = (gn < N) ? W[(size_t)gk2 * N + gn] : 0.f;
    }
    __syncthreads();
#pragma unroll
    for (int kk = 0; kk < 16; ++kk) {
      float a[4], b[4];
#pragma unroll
      for (int i = 0; i < 4; ++i) a[i] = As[kk][tm * 4 + i];
#pragma unroll
      for (int j = 0; j < 4; ++j) b[j] = Ws[kk][tn * 4 + j];
#pragma unroll
      for (int i = 0; i < 4; ++i)
#pragma unroll
        for (int j = 0; j < 4; ++j) acc[i][j] += a[i] * b[j];
    }
    __syncthreads();
  }
#pragma unroll
  for (int i = 0; i < 4; ++i) {
    int gm = m0 + tm * 4 + i;
    if (gm >= M) continue;
#pragma unroll
    for (int j = 0; j < 4; ++j) {
      int gn = n0 + tn * 4 + j;
      if (gn >= N) continue;
      C[(size_t)gm * N + gn] = acc[i][j] + bias[gn];
    }
  }
}

// ---------------- residual + LN: one wave per row ----------------
template <bool RES>
__global__ __launch_bounds__(256) void ln_kernel(const float* __restrict__ x,
                                                 const float* __restrict__ r,
                                                 const float* __restrict__ s,
                                                 const float* __restrict__ b,
                                                 float* __restrict__ out, int nrows) {
  const int wave = threadIdx.x >> 6, lane = threadIdx.x & 63;
  const int row = blockIdx.x * 4 + wave;
  if (row >= nrows) return;
  f4v v = *((const f4v*)(x + (size_t)row * D_) + lane);
  if (RES) {
    f4v rv = *((const f4v*)(r + (size_t)row * D_) + lane);
    v[0] += rv[0]; v[1] += rv[1]; v[2] += rv[2]; v[3] += rv[3];
  }
  float sum = v[0] + v[1] + v[2] + v[3];
#pragma unroll
  for (int off = 32; off > 0; off >>= 1) sum += __shfl_xor(sum, off, 64);
  float mean = sum * (1.f / D_);
  float c0 = v[0] - mean, c1 = v[1] - mean, c2 = v[2] - mean, c3 = v[3] - mean;
  float vs = c0 * c0 + c1 * c1 + c2 * c2 + c3 * c3;
#pragma unroll
  for (int off = 32; off > 0; off >>= 1) vs += __shfl_xor(vs, off, 64);
  float inv = rsqrtf(vs * (1.f / D_) + 1e-5f);
  f4v sv = *((const f4v*)s + lane);
  f4v bv = *((const f4v*)b + lane);
  f4v o;
  o[0] = c0 * inv * sv[0] + bv[0];
  o[1] = c1 * inv * sv[1] + bv[1];
  o[2] = c2 * inv * sv[2] + bv[2];
  o[3] = c3 * inv * sv[3] + bv[3];
  *((f4v*)(out + (size_t)row * D_) + lane) = o;
}

// ---------------- MFMA flash attention ----------------
template <bool BIAS, bool KVBF16, bool SPLIT>
__global__ __launch_bounds__(256) void mattn_kernel(
    const float* __restrict__ qb, int ldq,
    const void* __restrict__ kbv, int ldk,
    const void* __restrict__ vbv, int ldv,
    const unsigned int* __restrict__ bits,
    float* __restrict__ outp, int P, int Pw, int tps, int S) {
  __shared__ __align__(16) short Kt[128 * 40];
  __shared__ __align__(16) short Vt[32 * 132];
  __shared__ __align__(16) short Pt[4 * 16 * 36];
  __shared__ unsigned int bb[64];
  __shared__ float Msh[4][16], Lsh[4][16];
  float* Osh = (float*)Kt;
  const int b = blockIdx.x >> 3, h = blockIdx.x & 7;
  const int q0 = blockIdx.y * 16;
  const int seg = blockIdx.z;
  const int kbeg = seg * tps * KT_;
  const int kend = min(P, kbeg + tps * KT_);
  const int t = threadIdx.x;
  const int lane = t & 63, w = t >> 6;
  const int lr = lane & 15, lg = lane >> 4;
  const float scale = 0.17677669529663687f;

  s8v qhf, qlf;
  {
    int qrow = q0 + lr; if (qrow >= Q_) qrow = Q_ - 1;
    const float* qp = qb + (size_t)(b * Q_ + qrow) * ldq + h * HD_;
#pragma unroll
    for (int e = 0; e < 8; ++e) {
      int d = 4 * lg + (e & 3) + 16 * (e >> 2);
      short hh, ll; split2(qp[d], hh, ll);
      qhf[e] = hh; qlf[e] = ll;
    }
  }
  float mreg[4], lreg[4];
  f4v accO0 = (f4v){0.f, 0.f, 0.f, 0.f}, accO1 = (f4v){0.f, 0.f, 0.f, 0.f};
#pragma unroll
  for (int i = 0; i < 4; ++i) { mreg[i] = -3.0e38f; lreg[i] = 0.f; }

  for (int k0 = kbeg; k0 < kend; k0 += KT_) {
    {
      const int key = t >> 1, dh = (t & 1) * 16;
      const int gk = k0 + key;
      s8v ka = {0,0,0,0,0,0,0,0}, kb2 = {0,0,0,0,0,0,0,0};
      s8v va = {0,0,0,0,0,0,0,0}, vb2 = {0,0,0,0,0,0,0,0};
      if (gk < kend) {
        if (KVBF16) {
          const unsigned short* kp = (const unsigned short*)kbv + (size_t)(b * P + gk) * ldk + h * HD_ + dh;
          const unsigned short* vp = (const unsigned short*)vbv + (size_t)(b * P + gk) * ldv + h * HD_ + dh;
          ka = *(const s8v*)kp; kb2 = *(const s8v*)(kp + 8);
          va = *(const s8v*)vp; vb2 = *(const s8v*)(vp + 8);
        } else {
          const float* kp = (const float*)kbv + (size_t)(b * P + gk) * ldk + h * HD_ + dh;
          const float* vp = (const float*)vbv + (size_t)(b * P + gk) * ldv + h * HD_ + dh;
#pragma unroll
          for (int j = 0; j < 8; ++j) {
            ka[j] = (short)f2bf(kp[j]); kb2[j] = (short)f2bf(kp[8 + j]);
            va[j] = (short)f2bf(vp[j]); vb2[j] = (short)f2bf(vp[8 + j]);
          }
        }
      }
      *(s8v*)&Kt[key * 40 + dh] = ka;
      *(s8v*)&Kt[key * 40 + dh + 8] = kb2;
#pragma unroll
      for (int j = 0; j < 8; ++j) {
        Vt[(dh + j) * 132 + key] = va[j];
        Vt[(dh + 8 + j) * 132 + key] = vb2[j];
      }
    }
    if (BIAS && t < 64) {
      int qq = t >> 2, wi = t & 3;
      int gr = q0 + qq, gw = (k0 >> 5) + wi;
      bb[t] = (gr < Q_ && gw < Pw) ? bits[(size_t)(b * Q_ + gr) * Pw + gw] : 0u;
    }
    __syncthreads();
    s8v kf0 = ldfrag(&Kt[(w * 32 + lr) * 40 + 4 * lg]);
    s8v kf1 = ldfrag(&Kt[(w * 32 + 16 + lr) * 40 + 4 * lg]);
    f4v accS0 = (f4v){0.f, 0.f, 0.f, 0.f}, accS1 = (f4v){0.f, 0.f, 0.f, 0.f};
    accS0 = __builtin_amdgcn_mfma_f32_16x16x32_bf16(qhf, kf0, accS0, 0, 0, 0);
    accS0 = __builtin_amdgcn_mfma_f32_16x16x32_bf16(qlf, kf0, accS0, 0, 0, 0);
    accS1 = __builtin_amdgcn_mfma_f32_16x16x32_bf16(qhf, kf1, accS1, 0, 0, 0);
    accS1 = __builtin_amdgcn_mfma_f32_16x16x32_bf16(qlf, kf1, accS1, 0, 0, 0);
    const int gk0 = k0 + w * 32 + lr;
#pragma unroll
    for (int i = 0; i < 4; ++i) {
      float s0 = accS0[i] * scale, s1 = accS1[i] * scale;
      if (BIAS) {
        unsigned int word = bb[(4 * lg + i) * 4 + w];
        if ((word >> lr) & 1u) s0 += -1e9f;
        if ((word >> (16 + lr)) & 1u) s1 += -1e9f;
      }
      if (gk0 >= kend) s0 = -3.0e38f;
      if (gk0 + 16 >= kend) s1 = -3.0e38f;
      float rm = fmaxf(s0, s1);
#pragma unroll
      for (int off = 1; off < 16; off <<= 1) rm = fmaxf(rm, __shfl_xor(rm, off, 64));
      float mn = fmaxf(mreg[i], rm);
      float corr = __expf(mreg[i] - mn);
      mreg[i] = mn;
      float p0 = __expf(s0 - mn), p1 = __expf(s1 - mn);
      lreg[i] = lreg[i] * corr + p0 + p1;
      accO0[i] *= corr;
      accO1[i] *= corr;
      Pt[w * 576 + (4 * lg + i) * 36 + lr] = (short)f2bf(p0);
      Pt[w * 576 + (4 * lg + i) * 36 + 16 + lr] = (short)f2bf(p1);
    }
    s8v pf = ldfrag(&Pt[w * 576 + lr * 36 + 4 * lg]);
    s8v vf0 = ldfrag(&Vt[lr * 132 + w * 32 + 4 * lg]);
    s8v vf1 = ldfrag(&Vt[(16 + lr) * 132 + w * 32 + 4 * lg]);
    accO0 = __builtin_amdgcn_mfma_f32_16x16x32_bf16(pf, vf0, accO0, 0, 0, 0);
    accO1 = __builtin_amdgcn_mfma_f32_16x16x32_bf16(pf, vf1, accO1, 0, 0, 0);
    __syncthreads();
  }
#pragma unroll
  for (int i = 0; i < 4; ++i) {
    float lv = lreg[i];
#pragma unroll
    for (int off = 1; off < 16; off <<= 1) lv += __shfl_xor(lv, off, 64);
    if (lr == 0) { Msh[w][4 * lg + i] = mreg[i]; Lsh[w][4 * lg + i] = lv; }
  }
#pragma unroll
  for (int i = 0; i < 4; ++i) {
    Osh[w * 528 + (4 * lg + i) * 33 + lr] = accO0[i];
    Osh[w * 528 + (4 * lg + i) * 33 + 16 + lr] = accO1[i];
  }
  __syncthreads();
  float* part = SPLIT
      ? outp + ((size_t)((blockIdx.x * gridDim.y + blockIdx.y) * S + seg)) * RECSZ
      : nullptr;
  for (int o = t; o < 512; o += 256) {
    int qq = o >> 5, d = o & 31;
    float M = fmaxf(fmaxf(Msh[0][qq], Msh[1][qq]), fmaxf(Msh[2][qq], Msh[3][qq]));
    float lt = 0.f, Ov = 0.f;
#pragma unroll
    for (int w4 = 0; w4 < 4; ++w4) {
      float wt = __expf(Msh[w4][qq] - M);
      lt += wt * Lsh[w4][qq];
      Ov += wt * Osh[w4 * 528 + qq * 33 + d];
    }
    if (SPLIT) {
      if (d == 0) { part[qq] = M; part[16 + qq] = lt; }
      part[32 + qq * 32 + d] = Ov;
    } else if (q0 + qq < Q_) {
      outp[(size_t)(b * Q_ + q0 + qq) * D_ + h * HD_ + d] = Ov / lt;
    }
  }
}

// ---------------- split-K combine ----------------
__global__ __launch_bounds__(256) void attncomb_kernel(
    const float* __restrict__ part, float* __restrict__ out, int S, int nqt) {
  const int row = blockIdx.x;
  const int b = row / Q_, qq = row % Q_;
  const int t = threadIdx.x;
  const int h = t >> 5, d = t & 31;
  const int qt = qq >> 4, r = qq & 15;
  const float* base = part + ((size_t)((b * 8 + h) * nqt + qt) * S) * RECSZ;
  float M = -3.0e38f;
  for (int s = 0; s < S; ++s) M = fmaxf(M, base[(size_t)s * RECSZ + r]);
  float lt = 0.f, Ov = 0.f;
  for (int s = 0; s < S; ++s) {
    const float* rec = base + (size_t)s * RECSZ;
    float w = __expf(rec[r] - M);
    lt += w * rec[16 + r];
    Ov += w * rec[32 + r * 32 + d];
  }
  out[(size_t)row * D_ + h * HD_ + d] = Ov / lt;
}

// ---------------- threshold + pack bias bits from rbias ----------------
__global__ __launch_bounds__(256) void packbits_kernel(
    const float* __restrict__ r, unsigned int* __restrict__ bias, int P, int ldr) {
  __shared__ float red[256];
  __shared__ unsigned int bw[128];
  const int row = blockIdx.x;
  const int b = row / Q_, qq = row % Q_;
  const int t = threadIdx.x;
  const float* src = r + (size_t)b * Q_ * ldr + (size_t)qq * ldr;
  const int Pw = (P + 31) >> 5;
  float nign = 0.f;
  for (int p = t; p < P; p += 256)
    if (!(src[p] < 0.f)) nign += 1.f;
  float tot = block_sum(nign, red);
  bool fully = (tot == 0.f);
  for (int w = t; w < Pw; w += 256) bw[w] = 0u;
  __syncthreads();
  if (!fully) {
    for (int p = t; p < P; p += 256) {
      if (src[p] < 0.f) atomicOr(&bw[p >> 5], 1u << (p & 31));
    }
  }
  __syncthreads();
  unsigned int* dst = bias + (size_t)row * Pw;
  for (int w = t; w < Pw; w += 256) dst[w] = bw[w];
}

// ---------------- host dispatch ----------------
static inline void mg(hipStream_t st, int bm, int amode, int wmode, bool relu,
                      const void* A, const void* W, const float* bias, void* C,
                      int M, int N, int K, int Z,
                      long long Abs, long long Wbs, long long Cbs, int ldc) {
  dim3 g(N / 128, (M + bm - 1) / bm, Z);
  if (bm == 32) {
    if (relu)
      mgemm_kernel<32, 0, 0, true, 0><<<g, 256, 0, st>>>(A, W, bias, C, M, N, K, Abs, Wbs, Cbs, ldc, 0);
    else
      mgemm_kernel<32, 0, 0, false, 0><<<g, 256, 0, st>>>(A, W, bias, C, M, N, K, Abs, Wbs, Cbs, ldc, 0);
  } else {
    if (amode == 1)
      mgemm_kernel<64, 1, 0, false, 1><<<g, 256, 0, st>>>(A, W, bias, C, M, N, K, Abs, Wbs, Cbs, ldc, 0);
    else
      mgemm_kernel<64, 0, 0, false, 0><<<g, 256, 0, st>>>(A, W, bias, C, M, N, K, Abs, Wbs, Cbs, ldc, 0);
  }
}

extern "C" void kernel_launch(void* const* d_in, const int* in_sizes, int n_in,
                              void* d_out, int out_size, void* d_ws, size_t ws_size,
                              hipStream_t stream) {
  const float* mask_features = (const float*)d_in[0];
  const float* mem[3] = {(const float*)d_in[1], (const float*)d_in[2], (const float*)d_in[3]};
  const float* qf = (const float*)d_in[4];
  const float* qe = (const float*)d_in[5];
  const float* ca_wqkv = (const float*)d_in[6];
  const float* ca_bqkv = (const float*)d_in[7];
  const float* ca_wo = (const float*)d_in[8];
  const float* ca_bo = (const float*)d_in[9];
  const float* ca_ln_s = (const float*)d_in[10];
  const float* ca_ln_b = (const float*)d_in[11];
  const float* sa_wqkv = (const float*)d_in[12];
  const float* sa_bqkv = (const float*)d_in[13];
  const float* sa_wo = (const float*)d_in[14];
  const float* sa_bo = (const float*)d_in[15];
  const float* sa_ln_s = (const float*)d_in[16];
  const float* sa_ln_b = (const float*)d_in[17];
  const float* ffn_w1 = (const float*)d_in[18];
  const float* ffn_b1 = (const float*)d_in[19];
  const float* ffn_w2 = (const float*)d_in[20];
  const float* ffn_b2 = (const float*)d_in[21];
  const float* ffn_ln_s = (const float*)d_in[22];
  const float* ffn_ln_b = (const float*)d_in[23];
  const float* dec_ln_s = (const float*)d_in[24];
  const float* dec_ln_b = (const float*)d_in[25];
  const float* me_w1 = (const float*)d_in[26];
  const float* me_b1 = (const float*)d_in[27];
  const float* me_w2 = (const float*)d_in[28];
  const float* me_b2 = (const float*)d_in[29];
  const float* me_w3 = (const float*)d_in[30];
  const float* me_b3 = (const float*)d_in[31];
  const float* cls_w = (const float*)d_in[32];
  const float* cls_b = (const float*)d_in[33];

  float* out_logits = (float*)d_out;
  float* out_mask = (float*)d_out + (size_t)800 * C_;

  float* fws = (float*)d_ws;
  float* q      = fws; fws += (size_t)800 * D_;
  float* qh     = fws; fws += (size_t)800 * D_;
  float* attn_o = fws; fws += (size_t)800 * D_;
  float* tmp    = fws; fws += (size_t)800 * D_;
  float* nq     = fws; fws += (size_t)800 * D_;
  float* me3    = fws; fws += (size_t)800 * D_;
  float* kvbuf  = fws; fws += (size_t)B_ * PMAX_ * 256;    // bf16 [B][P][512]
  float* qkvbuf = fws; fws += (size_t)800 * 768;
  float* biasb  = fws; fws += (size_t)800 * 128;
  float* ffnh   = fws; fws += (size_t)B_ * Q_ * F_;
  float* part   = fws; fws += (size_t)64 * 7 * 3 * RECSZ;
  float* rmf0   = fws; fws += (size_t)B_ * 256 * 196;
  float* rmf1   = fws; fws += (size_t)B_ * 256 * 784;
  float* rmf2   = fws; fws += (size_t)B_ * 256 * 3136;
  float* rbias  = fws; fws += (size_t)B_ * Q_ * 3200;

  unsigned short* kvb = (unsigned short*)kvbuf;
  unsigned int* biasbits = (unsigned int*)biasb;

  short* sws = (short*)fws;
  short* W2ca  = sws; sws += (size_t)27 * 256 * 512;
  short* W2sa  = sws; sws += (size_t)27 * 256 * 512;
  short* W2cao = sws; sws += (size_t)9 * 256 * 512;
  short* W2sao = sws; sws += (size_t)9 * 256 * 512;
  short* W2f1  = sws; sws += (size_t)9 * 2048 * 512;
  short* W2f2  = sws; sws += (size_t)9 * 256 * 4096;
  short* W2me  = sws; sws += (size_t)3 * 256 * 512;
  short* mem2s = sws; sws += (size_t)B_ * 3136 * 512;
  short* mem1s = sws; sws += (size_t)B_ * 784 * 512;
  short* mem0s = sws; sws += (size_t)B_ * 196 * 512;
  short* memsp[3] = {mem0s, mem1s, mem2s};
  short* rmfs0 = sws; sws += (size_t)B_ * 256 * 512;
  short* rmfs1 = sws; sws += (size_t)B_ * 896 * 512;
  short* rmfs2 = sws; sws += (size_t)B_ * 3200 * 512;
  short* rmfs[3] = {rmfs0, rmfs1, rmfs2};

  tsplit_kernel<<<dim3(8, 8, 27), 256, 0, stream>>>(ca_wqkv, W2ca, 256, 256, 65536, 131072);
  tsplit_kernel<<<dim3(8, 8, 27), 256, 0, stream>>>(sa_wqkv, W2sa, 256, 256, 65536, 131072);
  tsplit_kernel<<<dim3(8, 8, 9), 256, 0, stream>>>(ca_wo, W2cao, 256, 256, 65536, 131072);
  tsplit_kernel<<<dim3(8, 8, 9), 256, 0, stream>>>(sa_wo, W2sao, 256, 256, 65536, 131072);
  tsplit_kernel<<<dim3(64, 8, 9), 256, 0, stream>>>(ffn_w1, W2f1, 256, 2048, 524288, 1048576);
  tsplit_kernel<<<dim3(8, 64, 9), 256, 0, stream>>>(ffn_w2, W2f2, 2048, 256, 524288, 1048576);
  tsplit_kernel<<<dim3(8, 8, 1), 256, 0, stream>>>(me_w1, W2me, 256, 256, 0, 0);
  tsplit_kernel<<<dim3(8, 8, 1), 256, 0, stream>>>(me_w2, W2me + 131072, 256, 256, 0, 0);
  tsplit_kernel<<<dim3(8, 8, 1), 256, 0, stream>>>(me_w3, W2me + 262144, 256, 256, 0, 0);
  tsplit_kernel<<<dim3(7, 8, 8), 256, 0, stream>>>(mem[0], mem0s, 256, 196, 256 * 196, 196 * 512);
  tsplit_kernel<<<dim3(25, 8, 8), 256, 0, stream>>>(mem[1], mem1s, 256, 784, 256 * 784, 784 * 512);
  tsplit_kernel<<<dim3(98, 8, 8), 256, 0, stream>>>(mem[2], mem2s, 256, 3136, 256 * 3136, 3136 * 512);

  // ---- resize mask_features once to 3 resolutions, then transpose-split (padded) ----
  resize3_kernel<<<2048, 256, 0, stream>>>(mask_features, rmf0, rmf1, rmf2);
  tsplitp_kernel<<<dim3(8, 8, 8), 256, 0, stream>>>(rmf0, rmfs0, 256, 196, 256,
                                                    256 * 196, 256 * 512);
  tsplitp_kernel<<<dim3(28, 8, 8), 256, 0, stream>>>(rmf1, rmfs1, 256, 784, 896,
                                                     256 * 784, 896 * 512);
  tsplitp_kernel<<<dim3(100, 8, 8), 256, 0, stream>>>(rmf2, rmfs2, 256, 3136, 3200,
                                                      256 * 3136, 3200 * 512);

  initq_kernel<<<800, 256, 0, stream>>>(qf, qe, q);

  const int Ps[3] = {196, 784, 3136};
  const int Ppad[3] = {256, 896, 3200};
  const int Ss[3] = {1, 2, 3};
  for (int i = 0; i < L_; ++i) {
    const int mi = i % 3, P = Ps[mi];
    const int Pw = (P + 31) >> 5;
    const int S = Ss[mi];
    const int ntiles = (P + KT_ - 1) / KT_;
    const int tps = (ntiles + S - 1) / S;
    // ---- cross-attention (biasbits prepared at end of previous layer) ----
    mg(stream, 32, 0, 0, false, q, W2ca + (size_t)(i * 3) * 131072, ca_bqkv + i * 768, qh,
       800, 256, 256, 1, 0, 0, 0, 256);
    mg(stream, 64, 1, 0, false, memsp[mi], W2ca + (size_t)(i * 3 + 1) * 131072,
       ca_bqkv + i * 768 + 256, kvb,
       P, 512, 256, B_, (long long)P * 512, 0, (long long)P * 512, 512);
    {
      dim3 ag(64, 7, S);
      if (S > 1) {
        if (i > 0)
          mattn_kernel<true, true, true><<<ag, 256, 0, stream>>>(
              qh, 256, kvb, 512, kvb + 256, 512, biasbits, part, P, Pw, tps, S);
        else
          mattn_kernel<false, true, true><<<ag, 256, 0, stream>>>(
              qh, 256, kvb, 512, kvb + 256, 512, nullptr, part, P, Pw, tps, S);
        attncomb_kernel<<<800, 256, 0, stream>>>(part, attn_o, S, 7);
      } else {
        if (i > 0)
          mattn_kernel<true, true, false><<<ag, 256, 0, stream>>>(
              qh, 256, kvb, 512, kvb + 256, 512, biasbits, attn_o, P, Pw, tps, S);
        else
          mattn_kernel<false, true, false><<<ag, 256, 0, stream>>>(
              qh, 256, kvb, 512, kvb + 256, 512, nullptr, attn_o, P, Pw, tps, S);
      }
    }
    mg(stream, 32, 0, 0, false, attn_o, W2cao + (size_t)i * 131072, ca_bo + i * 256, tmp,
       800, 256, 256, 1, 0, 0, 0, 256);
    ln_kernel<true><<<200, 256, 0, stream>>>(tmp, q, ca_ln_s + i * 256, ca_ln_b + i * 256, q, 800);
    // ---- self-attention ----
    mg(stream, 32, 0, 0, false, q, W2sa + (size_t)(i * 3) * 131072, sa_bqkv + i * 768, qkvbuf,
       800, 768, 256, 1, 0, 0, 0, 768);
    mattn_kernel<false, false, false><<<dim3(64, 7, 1), 256, 0, stream>>>(
        qkvbuf, 768, qkvbuf + 256, 768, qkvbuf + 512, 768, nullptr, attn_o, 100, 4, 1, 1);
    mg(stream, 32, 0, 0, false, attn_o, W2sao + (size_t)i * 131072, sa_bo + i * 256, tmp,
       800, 256, 256, 1, 0, 0, 0, 256);
    ln_kernel<true><<<200, 256, 0, stream>>>(tmp, q, sa_ln_s + i * 256, sa_ln_b + i * 256, q, 800);
    // ---- FFN ----
    mg(stream, 32, 0, 0, true, q, W2f1 + (size_t)i * 1048576, ffn_b1 + i * 2048, ffnh,
       800, 2048, 256, 1, 0, 0, 0, 2048);
    mg(stream, 32, 0, 0, false, ffnh, W2f2 + (size_t)i * 1048576, ffn_b2 + i * 256, tmp,
       800, 256, 2048, 1, 0, 0, 0, 256);
    ln_kernel<true><<<200, 256, 0, stream>>>(tmp, q, ffn_ln_s + i * 256, ffn_ln_b + i * 256, q, 800);
    // ---- fused mask head (dec_ln + me1 + me2 + me3) ----
    maskhead_kernel<<<50, 256, 0, stream>>>(q, dec_ln_s, dec_ln_b, W2me,
                                            me_b1, me_b2, me_b3, nq, me3);
    if (i < L_ - 1) {
      // ---- bias for NEXT layer: me3 @ resized-mask-features, then threshold+pack ----
      const int mn = (i + 1) % 3;
      const int Pn = Ps[mn], Pp = Ppad[mn];
      mgemm_kernel<32, 0, 0, false, 0><<<dim3(Pp / 128, 4, 8), 256, 0, stream>>>(
          me3, rmfs[mn], nullptr, rbias, 100, Pp, 256,
          (long long)100 * 256, (long long)Pp * 512, (long long)100 * Pp, Pp, 0);
      packbits_kernel<<<800, 256, 0, stream>>>(rbias, biasbits, Pn, Pp);
    } else {
      // ---- final layer: full-resolution pred_mask einsum (only once per call) ----
      mgemm_kernel<64, 0, 1, false, 0><<<dim3(2, 98, 8), 256, 0, stream>>>(
          me3, mask_features, nullptr, out_mask, 100, 12544, 256,
          (long long)100 * 256, (long long)256 * 12544, (long long)100 * 12544, 12544, 1);
    }
  }
  gemm32_kernel<<<dim3(3, 13, 1), 256, 0, stream>>>(nq, cls_w, cls_b, out_logits, 800, C_, 256);
}

// Round 17
// 2776.263 us; speedup vs baseline: 1.0032x; 1.0032x over previous
//
#include <hip/hip_runtime.h>
#include <cmath>

#define B_ 8
#define Q_ 100
#define D_ 256
#define H_ 8
#define HD_ 32
#define L_ 9
#define F_ 2048
#define C_ 151
#define HM_ 112
#define PMAX_ 3136
#define KT_ 128
#define RECSZ 544   // 16 m + 16 l + 16*32 O
#define PMS 116     // LDS plane stride (mult of 4, good bank spread)

typedef __attribute__((ext_vector_type(4))) short s4v;
typedef __attribute__((ext_vector_type(8))) short s8v;
typedef __attribute__((ext_vector_type(4))) float f4v;

__device__ __forceinline__ unsigned short f2bf(float x) {
  unsigned int u = __float_as_uint(x);
  return (unsigned short)((u + 0x7fffu + ((u >> 16) & 1u)) >> 16);
}
__device__ __forceinline__ float bf2f(unsigned short h) {
  return __uint_as_float(((unsigned int)h) << 16);
}
__device__ __forceinline__ void split2(float x, short& h, short& l) {
  unsigned short hb = f2bf(x);
  float r = x - bf2f(hb);
  h = (short)hb;
  l = (short)f2bf(r);
}

__device__ __forceinline__ float block_sum(float v, float* red) {
  int t = threadIdx.x;
  red[t] = v; __syncthreads();
  for (int s = 128; s > 0; s >>= 1) {
    if (t < s) red[t] += red[t + s];
    __syncthreads();
  }
  float r = red[0]; __syncthreads();
  return r;
}

// ---------------- init q ----------------
__global__ __launch_bounds__(256) void initq_kernel(const float* __restrict__ qf,
                                                    const float* __restrict__ qe,
                                                    float* __restrict__ q) {
  int idx = blockIdx.x * 256 + threadIdx.x;
  int qd = idx % (Q_ * D_);
  q[idx] = qf[qd] + qe[qd];
}

// ---------------- per-channel antialias resize ----------------
template <int OH>
__device__ __forceinline__ void resize_plane(const float* __restrict__ pm,
                                             float* __restrict__ out,
                                             float* wbuf, int* sbuf, int t) {
  constexpr int RATIO = HM_ / OH;
  constexpr int TAPS = 2 * RATIO;
  constexpr float INVR = 1.f / (float)RATIO;
  if (t < OH) {
    float s = ((float)t + 0.5f) * RATIO - 0.5f;
    int x0 = (int)floorf(s - RATIO) + 1;
    sbuf[t] = x0;
    float ws = 0.f;
#pragma unroll
    for (int si = 0; si < TAPS; ++si) {
      int x = x0 + si;
      float w = (x >= 0 && x < HM_) ? 1.f - fabsf(s - (float)x) * INVR : 0.f;
      wbuf[t * TAPS + si] = w;
      ws += w;
    }
    float inv = 1.f / ws;
#pragma unroll
    for (int si = 0; si < TAPS; ++si) wbuf[t * TAPS + si] *= inv;
  }
  __syncthreads();
  for (int p = t; p < OH * OH; p += 256) {
    int oy = p / OH, ox = p - oy * OH;
    int x0 = sbuf[ox], y0 = sbuf[oy];
    const float* wx = &wbuf[ox * TAPS];
    const float* wy = &wbuf[oy * TAPS];
    float acc = 0.f;
#pragma unroll
    for (int ti = 0; ti < TAPS; ++ti) {
      int y = min(max(y0 + ti, 0), HM_ - 1);
      const float* pr = pm + y * PMS;
      float ra0 = 0.f, ra1 = 0.f;
#pragma unroll
      for (int si = 0; si < TAPS; si += 2) {
        int xa = min(max(x0 + si, 0), HM_ - 1);
        int xb = min(max(x0 + si + 1, 0), HM_ - 1);
        ra0 += wx[si] * pr[xa];
        ra1 += wx[si + 1] * pr[xb];
      }
      acc += wy[ti] * (ra0 + ra1);
    }
    out[p] = acc;
  }
  __syncthreads();
}

__global__ __launch_bounds__(256) void resize3_kernel(
    const float* __restrict__ mf, float* __restrict__ r0,
    float* __restrict__ r1, float* __restrict__ r2) {
  __shared__ float pm[HM_ * PMS];
  __shared__ float wbuf[224];
  __shared__ int sbuf[56];
  const int bd = blockIdx.x;
  const float* pl = mf + (size_t)bd * (HM_ * HM_);
  const int t = threadIdx.x;
  for (int f = t; f < (HM_ * HM_) / 4; f += 256) {
    int row = f / 28, c = (f - row * 28) * 4;
    *(f4v*)&pm[row * PMS + c] = ((const f4v*)pl)[f];
  }
  __syncthreads();
  resize_plane<14>(pm, r0 + (size_t)bd * 196, wbuf, sbuf, t);
  resize_plane<28>(pm, r1 + (size_t)bd * 784, wbuf, sbuf, t);
  resize_plane<56>(pm, r2 + (size_t)bd * 3136, wbuf, sbuf, t);
}

// ---------------- transpose-split: fp32 [K][N] -> bf16 [N][2K] ----------------
__global__ __launch_bounds__(256) void tsplit_kernel(
    const float* __restrict__ in, short* __restrict__ out,
    int K, int N, long long ibs, long long obs) {
  __shared__ float tile[32][33];
  const int z = blockIdx.z;
  const int nb = blockIdx.x * 32, kb = blockIdx.y * 32;
  const float* I = in + (size_t)z * ibs;
  short* O = out + (size_t)z * obs;
  const int t = threadIdx.x;
  {
    const int r = t >> 3, c = (t & 7) * 4;
    const int gk = kb + r;
#pragma unroll
    for (int j = 0; j < 4; ++j) {
      int gn = nb + c + j;
      tile[r][c + j] = (gk < K && gn < N) ? I[(size_t)gk * N + gn] : 0.f;
    }
  }
  __syncthreads();
  {
    const int nr = t >> 3, kc = (t & 7) * 4;
    const int gn = nb + nr;
    if (gn < N) {
#pragma unroll
      for (int j = 0; j < 4; ++j) {
        int gk = kb + kc + j;
        if (gk < K) {
          short h, l; split2(tile[kc + j][nr], h, l);
          O[(size_t)gn * 2 * K + gk] = h;
          O[(size_t)gn * 2 * K + K + gk] = l;
        }
      }
    }
  }
}

// ---------------- transpose-split with zero pad: N real -> Na alloc ----------------
__global__ __launch_bounds__(256) void tsplitp_kernel(
    const float* __restrict__ in, short* __restrict__ out,
    int K, int N, int Na, long long ibs, long long obs) {
  __shared__ float tile[32][33];
  const int z = blockIdx.z;
  const int nb = blockIdx.x * 32, kb = blockIdx.y * 32;
  const float* I = in + (size_t)z * ibs;
  short* O = out + (size_t)z * obs;
  const int t = threadIdx.x;
  {
    const int r = t >> 3, c = (t & 7) * 4;
    const int gk = kb + r;
#pragma unroll
    for (int j = 0; j < 4; ++j) {
      int gn = nb + c + j;
      tile[r][c + j] = (gk < K && gn < N) ? I[(size_t)gk * N + gn] : 0.f;
    }
  }
  __syncthreads();
  {
    const int nr = t >> 3, kc = (t & 7) * 4;
    const int gn = nb + nr;
    if (gn < Na) {
#pragma unroll
      for (int j = 0; j < 4; ++j) {
        int gk = kb + kc + j;
        if (gk < K) {
          short h, l; split2(tile[kc + j][nr], h, l);
          O[(size_t)gn * 2 * K + gk] = h;
          O[(size_t)gn * 2 * K + K + gk] = l;
        }
      }
    }
  }
}

// ---------------- MFMA frag load ----------------
__device__ __forceinline__ s8v ldfrag(const short* p) {
  s4v lo = *(const s4v*)p;
  s4v hi = *(const s4v*)(p + 16);
  return __builtin_shufflevector(lo, hi, 0, 1, 2, 3, 4, 5, 6, 7);
}

// ---------------- MFMA bf16x3 GEMM ----------------
template <int BM, int AMODE, int WMODE, bool RELU, int OUT>
__global__ __launch_bounds__(256) void mgemm_kernel(
    const void* __restrict__ Ap, const void* __restrict__ Wp,
    const float* __restrict__ bias, void* __restrict__ Cv,
    int M, int N, int K,
    long long Abs, long long Wbs, long long Cbs, int ldc, int swap) {
  constexpr int MI = BM / 32;
  __shared__ short Ah[BM * 36], Al[BM * 36], Wh[128 * 36], Wl[128 * 36];
  const int z = blockIdx.z;
  const int bx = swap ? blockIdx.y : blockIdx.x;
  const int by = swap ? blockIdx.x : blockIdx.y;
  const int n0 = bx * 128, m0 = by * BM;
  const int t = threadIdx.x;
  const int lane = t & 63;
  const int wave = t >> 6;
  const int wm = wave >> 1, wn = wave & 1;
  const int lr = lane & 15, lg = lane >> 4;
  f4v acc[MI][4];
#pragma unroll
  for (int i = 0; i < MI; ++i)
#pragma unroll
    for (int j = 0; j < 4; ++j) acc[i][j] = (f4v){0.f, 0.f, 0.f, 0.f};

  for (int k0 = 0; k0 < K; k0 += 32) {
    if (AMODE == 0) {
      const float* A = (const float*)Ap + (size_t)z * Abs;
      if (BM == 64) {
        const int arow = t >> 2;
        const int kc = (t & 3) * 8;
        float x[8];
        if (m0 + arow < M) {
          const float* ap = A + (size_t)(m0 + arow) * K + k0 + kc;
          *(f4v*)&x[0] = *(const f4v*)ap;
          *(f4v*)&x[4] = *(const f4v*)(ap + 4);
        } else {
#pragma unroll
          for (int e = 0; e < 8; ++e) x[e] = 0.f;
        }
        s4v h0, h1, l0, l1;
#pragma unroll
        for (int e = 0; e < 4; ++e) { short hh, ll; split2(x[e], hh, ll); h0[e] = hh; l0[e] = ll; }
#pragma unroll
        for (int e = 0; e < 4; ++e) { short hh, ll; split2(x[4 + e], hh, ll); h1[e] = hh; l1[e] = ll; }
        *(s4v*)&Ah[arow * 36 + kc] = h0; *(s4v*)&Ah[arow * 36 + kc + 4] = h1;
        *(s4v*)&Al[arow * 36 + kc] = l0; *(s4v*)&Al[arow * 36 + kc + 4] = l1;
      } else {
        const int arow = t >> 3;
        const int kc = (t & 7) * 4;
        float x[4];
        if (m0 + arow < M) {
          *(f4v*)&x[0] = *(const f4v*)(A + (size_t)(m0 + arow) * K + k0 + kc);
        } else {
#pragma unroll
          for (int e = 0; e < 4; ++e) x[e] = 0.f;
        }
        s4v h0, l0;
#pragma unroll
        for (int e = 0; e < 4; ++e) { short hh, ll; split2(x[e], hh, ll); h0[e] = hh; l0[e] = ll; }
        *(s4v*)&Ah[arow * 36 + kc] = h0;
        *(s4v*)&Al[arow * 36 + kc] = l0;
      }
    } else {
      const short* A2 = (const short*)Ap + (size_t)z * Abs;
      const int arow = t >> 2;
      const int c = t & 3, sel = c >> 1, ko = (c & 1) * 16;
      s8v v0 = {0, 0, 0, 0, 0, 0, 0, 0}, v1 = {0, 0, 0, 0, 0, 0, 0, 0};
      if (m0 + arow < M) {
        const short* ap = A2 + (size_t)(m0 + arow) * (2 * K) + sel * K + k0 + ko;
        v0 = *(const s8v*)ap;
        v1 = *(const s8v*)(ap + 8);
      }
      short* dst = sel ? Al : Ah;
      *(s4v*)&dst[arow * 36 + ko] = __builtin_shufflevector(v0, v0, 0, 1, 2, 3);
      *(s4v*)&dst[arow * 36 + ko + 4] = __builtin_shufflevector(v0, v0, 4, 5, 6, 7);
      *(s4v*)&dst[arow * 36 + ko + 8] = __builtin_shufflevector(v1, v1, 0, 1, 2, 3);
      *(s4v*)&dst[arow * 36 + ko + 12] = __builtin_shufflevector(v1, v1, 4, 5, 6, 7);
    }
    if (WMODE == 0) {
      const short* W2 = (const short*)Wp + (size_t)z * Wbs;
      const int n = t >> 1, sel = t & 1;
      const short* wp = W2 + (size_t)(n0 + n) * (2 * K) + sel * K + k0;
      short* dst = sel ? Wl : Wh;
#pragma unroll
      for (int j = 0; j < 4; ++j) {
        s8v v = *(const s8v*)(wp + j * 8);
        *(s4v*)&dst[n * 36 + j * 8] = __builtin_shufflevector(v, v, 0, 1, 2, 3);
        *(s4v*)&dst[n * 36 + j * 8 + 4] = __builtin_shufflevector(v, v, 4, 5, 6, 7);
      }
    } else {
      const float* W = (const float*)Wp + (size_t)z * Wbs;
      const int kr = t >> 3, c0 = (t & 7) * 16;
      const float* wp = W + (size_t)(k0 + kr) * N + n0 + c0;
      float x[16];
#pragma unroll
      for (int j = 0; j < 4; ++j) *(f4v*)&x[j * 4] = *(const f4v*)(wp + j * 4);
#pragma unroll
      for (int j = 0; j < 16; ++j) {
        short hh, ll; split2(x[j], hh, ll);
        Wh[(c0 + j) * 36 + kr] = hh;
        Wl[(c0 + j) * 36 + kr] = ll;
      }
    }
    __syncthreads();
    s8v whf[4], wlf[4];
#pragma unroll
    for (int ni = 0; ni < 4; ++ni) {
      whf[ni] = ldfrag(&Wh[(wn * 64 + ni * 16 + lr) * 36 + 4 * lg]);
      wlf[ni] = ldfrag(&Wl[(wn * 64 + ni * 16 + lr) * 36 + 4 * lg]);
    }
#pragma unroll
    for (int mi = 0; mi < MI; ++mi) {
      s8v ah = ldfrag(&Ah[(wm * (BM / 2) + mi * 16 + lr) * 36 + 4 * lg]);
      s8v al = ldfrag(&Al[(wm * (BM / 2) + mi * 16 + lr) * 36 + 4 * lg]);
#pragma unroll
      for (int ni = 0; ni < 4; ++ni) {
        acc[mi][ni] = __builtin_amdgcn_mfma_f32_16x16x32_bf16(ah, whf[ni], acc[mi][ni], 0, 0, 0);
        acc[mi][ni] = __builtin_amdgcn_mfma_f32_16x16x32_bf16(al, whf[ni], acc[mi][ni], 0, 0, 0);
        acc[mi][ni] = __builtin_amdgcn_mfma_f32_16x16x32_bf16(ah, wlf[ni], acc[mi][ni], 0, 0, 0);
      }
    }
    __syncthreads();
  }
  float* Cf = (float*)Cv + (size_t)z * Cbs;
  unsigned short* Ch = (unsigned short*)Cv + (size_t)z * Cbs;
#pragma unroll
  for (int mi = 0; mi < MI; ++mi) {
#pragma unroll
    for (int i = 0; i < 4; ++i) {
      int row = m0 + wm * (BM / 2) + mi * 16 + 4 * lg + i;
      if (row >= M) continue;
#pragma unroll
      for (int ni = 0; ni < 4; ++ni) {
        int col = n0 + wn * 64 + ni * 16 + lr;
        float v = acc[mi][ni][i] + (bias ? bias[col] : 0.f);
        if (RELU) v = fmaxf(v, 0.f);
        if (OUT == 0) Cf[(size_t)row * ldc + col] = v;
        else Ch[(size_t)row * ldc + col] = f2bf(v);
      }
    }
  }
}

// ---------------- fused mask head: dec_ln + me1 + me2 + me3 ----------------
__global__ __launch_bounds__(256) void maskhead_kernel(
    const float* __restrict__ q, const float* __restrict__ lns,
    const float* __restrict__ lnb, const short* __restrict__ W123,
    const float* __restrict__ b1, const float* __restrict__ b2,
    const float* __restrict__ b3,
    float* __restrict__ nqout, float* __restrict__ me3out) {
  __shared__ float Xb[16 * 264], Yb[16 * 264];
  __shared__ short Ah[16 * 36], Al[16 * 36], Wh[256 * 36], Wl[256 * 36];
  const int r0 = blockIdx.x * 16;
  const int t = threadIdx.x;
  const int lane = t & 63, w = t >> 6;
  const int lr = lane & 15, lg = lane >> 4;
#pragma unroll
  for (int rr = 0; rr < 4; ++rr) {
    int row = w * 4 + rr;
    int grow = r0 + row;
    f4v v = *((const f4v*)(q + (size_t)grow * D_) + lane);
    float sum = v[0] + v[1] + v[2] + v[3];
#pragma unroll
    for (int off = 32; off > 0; off >>= 1) sum += __shfl_xor(sum, off, 64);
    float mean = sum * (1.f / D_);
    float c0 = v[0] - mean, c1 = v[1] - mean, c2 = v[2] - mean, c3 = v[3] - mean;
    float vs = c0 * c0 + c1 * c1 + c2 * c2 + c3 * c3;
#pragma unroll
    for (int off = 32; off > 0; off >>= 1) vs += __shfl_xor(vs, off, 64);
    float inv = rsqrtf(vs * (1.f / D_) + 1e-5f);
    f4v sv = *((const f4v*)lns + lane);
    f4v bv = *((const f4v*)lnb + lane);
    f4v o;
    o[0] = c0 * inv * sv[0] + bv[0];
    o[1] = c1 * inv * sv[1] + bv[1];
    o[2] = c2 * inv * sv[2] + bv[2];
    o[3] = c3 * inv * sv[3] + bv[3];
    *(f4v*)&Xb[row * 264 + lane * 4] = o;
    *((f4v*)(nqout + (size_t)grow * D_) + lane) = o;
  }
  __syncthreads();
  float* src = Xb;
  float* dst = Yb;
  for (int s = 0; s < 3; ++s) {
    const short* Ws = W123 + (size_t)s * 131072;
    const float* bs = (s == 0) ? b1 : ((s == 1) ? b2 : b3);
    f4v acc[4];
#pragma unroll
    for (int j = 0; j < 4; ++j) acc[j] = (f4v){0.f, 0.f, 0.f, 0.f};
    for (int k0 = 0; k0 < 256; k0 += 32) {
      {
        int idx = t * 2;
        int row = idx >> 5, kc = idx & 31;
        short h0, l0, h1, l1;
        split2(src[row * 264 + k0 + kc], h0, l0);
        split2(src[row * 264 + k0 + kc + 1], h1, l1);
        Ah[row * 36 + kc] = h0; Ah[row * 36 + kc + 1] = h1;
        Al[row * 36 + kc] = l0; Al[row * 36 + kc + 1] = l1;
      }
      {
        const short* wp = Ws + (size_t)t * 512 + k0;
#pragma unroll
        for (int j = 0; j < 8; ++j)
          *(s4v*)&Wh[t * 36 + j * 4] = *(const s4v*)(wp + j * 4);
        const short* wpl = wp + 256;
#pragma unroll
        for (int j = 0; j < 8; ++j)
          *(s4v*)&Wl[t * 36 + j * 4] = *(const s4v*)(wpl + j * 4);
      }
      __syncthreads();
      s8v ah = ldfrag(&Ah[lr * 36 + 4 * lg]);
      s8v al = ldfrag(&Al[lr * 36 + 4 * lg]);
#pragma unroll
      for (int ni = 0; ni < 4; ++ni) {
        s8v wh = ldfrag(&Wh[(w * 64 + ni * 16 + lr) * 36 + 4 * lg]);
        s8v wl = ldfrag(&Wl[(w * 64 + ni * 16 + lr) * 36 + 4 * lg]);
        acc[ni] = __builtin_amdgcn_mfma_f32_16x16x32_bf16(ah, wh, acc[ni], 0, 0, 0);
        acc[ni] = __builtin_amdgcn_mfma_f32_16x16x32_bf16(al, wh, acc[ni], 0, 0, 0);
        acc[ni] = __builtin_amdgcn_mfma_f32_16x16x32_bf16(ah, wl, acc[ni], 0, 0, 0);
      }
      __syncthreads();
    }
#pragma unroll
    for (int ni = 0; ni < 4; ++ni) {
#pragma unroll
      for (int i = 0; i < 4; ++i) {
        int row = 4 * lg + i;
        int col = w * 64 + ni * 16 + lr;
        float v = acc[ni][i] + bs[col];
        if (s < 2) v = fmaxf(v, 0.f);
        dst[row * 264 + col] = v;
      }
    }
    __syncthreads();
    float* tmpp = src; src = dst; dst = tmpp;
  }
  for (int o = t; o < 16 * 256; o += 256) {
    int row = o >> 8, col = o & 255;
    me3out[(size_t)(r0 + row) * D_ + col] = src[row * 264 + col];
  }
}

// ---------------- fp32 GEMM (cls head only) ----------------
__global__ __launch_bounds__(256) void gemm32_kernel(
    const float* __restrict__ A, const float* __restrict__ W,
    const float* __restrict__ bias, float* __restrict__ C,
    int M, int N, int K) {
  __shared__ float As[16][65];
  __shared__ float Ws[16][65];
  const int n0 = blockIdx.x * 64, m0 = blockIdx.y * 64;
  const int t = threadIdx.x;
  const int tm = t >> 4, tn = t & 15;
  float acc[4][4] = {};
  for (int k0 = 0; k0 < K; k0 += 16) {
#pragma unroll
    for (int l = 0; l < 4; ++l) {
      int idx = t + l * 256;
      int am = idx >> 4, ak = idx & 15;
      int gm = m0 + am, gk = k0 + ak;
      As[ak][am] = (gm < M) ? A[(size_t)gm * K + gk] : 0.f;
      int wk = idx >> 6, wn = idx & 63;
      int gn = n0 + wn, gk2 = k0 + wk;
      Ws[wk][wn] = (gn < N) ? W[(size_t)gk2 * N + gn] : 0.f;
    }
    __syncthreads();
#pragma unroll
    for (int kk = 0; kk < 16; ++kk) {
      float a[4], b[4];
#pragma unroll
      for (int i = 0; i < 4; ++i) a[i] = As[kk][tm * 4 + i];
#pragma unroll
      for (int j = 0; j < 4; ++j) b[j] = Ws[kk][tn * 4 + j];
#pragma unroll
      for (int i = 0; i < 4; ++i)
#pragma unroll
        for (int j = 0; j < 4; ++j) acc[i][j] += a[i] * b[j];
    }
    __syncthreads();
  }
#pragma unroll
  for (int i = 0; i < 4; ++i) {
    int gm = m0 + tm * 4 + i;
    if (gm >= M) continue;
#pragma unroll
    for (int j = 0; j < 4; ++j) {
      int gn = n0 + tn * 4 + j;
      if (gn >= N) continue;
      C[(size_t)gm * N + gn] = acc[i][j] + bias[gn];
    }
  }
}

// ---------------- residual + LN: one wave per row ----------------
template <bool RES>
__global__ __launch_bounds__(256) void ln_kernel(const float* __restrict__ x,
                                                 const float* __restrict__ r,
                                                 const float* __restrict__ s,
                                                 const float* __restrict__ b,
                                                 float* __restrict__ out, int nrows) {
  const int wave = threadIdx.x >> 6, lane = threadIdx.x & 63;
  const int row = blockIdx.x * 4 + wave;
  if (row >= nrows) return;
  f4v v = *((const f4v*)(x + (size_t)row * D_) + lane);
  if (RES) {
    f4v rv = *((const f4v*)(r + (size_t)row * D_) + lane);
    v[0] += rv[0]; v[1] += rv[1]; v[2] += rv[2]; v[3] += rv[3];
  }
  float sum = v[0] + v[1] + v[2] + v[3];
#pragma unroll
  for (int off = 32; off > 0; off >>= 1) sum += __shfl_xor(sum, off, 64);
  float mean = sum * (1.f / D_);
  float c0 = v[0] - mean, c1 = v[1] - mean, c2 = v[2] - mean, c3 = v[3] - mean;
  float vs = c0 * c0 + c1 * c1 + c2 * c2 + c3 * c3;
#pragma unroll
  for (int off = 32; off > 0; off >>= 1) vs += __shfl_xor(vs, off, 64);
  float inv = rsqrtf(vs * (1.f / D_) + 1e-5f);
  f4v sv = *((const f4v*)s + lane);
  f4v bv = *((const f4v*)b + lane);
  f4v o;
  o[0] = c0 * inv * sv[0] + bv[0];
  o[1] = c1 * inv * sv[1] + bv[1];
  o[2] = c2 * inv * sv[2] + bv[2];
  o[3] = c3 * inv * sv[3] + bv[3];
  *((f4v*)(out + (size_t)row * D_) + lane) = o;
}

// ---------------- MFMA flash attention ----------------
template <bool BIAS, bool KVBF16, bool SPLIT>
__global__ __launch_bounds__(256) void mattn_kernel(
    const float* __restrict__ qb, int ldq,
    const void* __restrict__ kbv, int ldk,
    const void* __restrict__ vbv, int ldv,
    const unsigned int* __restrict__ bits,
    float* __restrict__ outp, int P, int Pw, int tps, int S) {
  __shared__ __align__(16) short Kt[128 * 40];
  __shared__ __align__(16) short Vt[32 * 132];
  __shared__ __align__(16) short Pt[4 * 16 * 36];
  __shared__ unsigned int bb[64];
  __shared__ float Msh[4][16], Lsh[4][16];
  float* Osh = (float*)Kt;
  const int b = blockIdx.x >> 3, h = blockIdx.x & 7;
  const int q0 = blockIdx.y * 16;
  const int seg = blockIdx.z;
  const int kbeg = seg * tps * KT_;
  const int kend = min(P, kbeg + tps * KT_);
  const int t = threadIdx.x;
  const int lane = t & 63, w = t >> 6;
  const int lr = lane & 15, lg = lane >> 4;
  const float scale = 0.17677669529663687f;

  s8v qhf, qlf;
  {
    int qrow = q0 + lr; if (qrow >= Q_) qrow = Q_ - 1;
    const float* qp = qb + (size_t)(b * Q_ + qrow) * ldq + h * HD_;
#pragma unroll
    for (int e = 0; e < 8; ++e) {
      int d = 4 * lg + (e & 3) + 16 * (e >> 2);
      short hh, ll; split2(qp[d], hh, ll);
      qhf[e] = hh; qlf[e] = ll;
    }
  }
  float mreg[4], lreg[4];
  f4v accO0 = (f4v){0.f, 0.f, 0.f, 0.f}, accO1 = (f4v){0.f, 0.f, 0.f, 0.f};
#pragma unroll
  for (int i = 0; i < 4; ++i) { mreg[i] = -3.0e38f; lreg[i] = 0.f; }

  for (int k0 = kbeg; k0 < kend; k0 += KT_) {
    {
      const int key = t >> 1, dh = (t & 1) * 16;
      const int gk = k0 + key;
      s8v ka = {0,0,0,0,0,0,0,0}, kb2 = {0,0,0,0,0,0,0,0};
      s8v va = {0,0,0,0,0,0,0,0}, vb2 = {0,0,0,0,0,0,0,0};
      if (gk < kend) {
        if (KVBF16) {
          const unsigned short* kp = (const unsigned short*)kbv + (size_t)(b * P + gk) * ldk + h * HD_ + dh;
          const unsigned short* vp = (const unsigned short*)vbv + (size_t)(b * P + gk) * ldv + h * HD_ + dh;
          ka = *(const s8v*)kp; kb2 = *(const s8v*)(kp + 8);
          va = *(const s8v*)vp; vb2 = *(const s8v*)(vp + 8);
        } else {
          const float* kp = (const float*)kbv + (size_t)(b * P + gk) * ldk + h * HD_ + dh;
          const float* vp = (const float*)vbv + (size_t)(b * P + gk) * ldv + h * HD_ + dh;
#pragma unroll
          for (int j = 0; j < 8; ++j) {
            ka[j] = (short)f2bf(kp[j]); kb2[j] = (short)f2bf(kp[8 + j]);
            va[j] = (short)f2bf(vp[j]); vb2[j] = (short)f2bf(vp[8 + j]);
          }
        }
      }
      *(s8v*)&Kt[key * 40 + dh] = ka;
      *(s8v*)&Kt[key * 40 + dh + 8] = kb2;
#pragma unroll
      for (int j = 0; j < 8; ++j) {
        Vt[(dh + j) * 132 + key] = va[j];
        Vt[(dh + 8 + j) * 132 + key] = vb2[j];
      }
    }
    if (BIAS && t < 64) {
      int qq = t >> 2, wi = t & 3;
      int gr = q0 + qq, gw = (k0 >> 5) + wi;
      bb[t] = (gr < Q_ && gw < Pw) ? bits[(size_t)(b * Q_ + gr) * Pw + gw] : 0u;
    }
    __syncthreads();
    s8v kf0 = ldfrag(&Kt[(w * 32 + lr) * 40 + 4 * lg]);
    s8v kf1 = ldfrag(&Kt[(w * 32 + 16 + lr) * 40 + 4 * lg]);
    f4v accS0 = (f4v){0.f, 0.f, 0.f, 0.f}, accS1 = (f4v){0.f, 0.f, 0.f, 0.f};
    accS0 = __builtin_amdgcn_mfma_f32_16x16x32_bf16(qhf, kf0, accS0, 0, 0, 0);
    accS0 = __builtin_amdgcn_mfma_f32_16x16x32_bf16(qlf, kf0, accS0, 0, 0, 0);
    accS1 = __builtin_amdgcn_mfma_f32_16x16x32_bf16(qhf, kf1, accS1, 0, 0, 0);
    accS1 = __builtin_amdgcn_mfma_f32_16x16x32_bf16(qlf, kf1, accS1, 0, 0, 0);
    const int gk0 = k0 + w * 32 + lr;
#pragma unroll
    for (int i = 0; i < 4; ++i) {
      float s0 = accS0[i] * scale, s1 = accS1[i] * scale;
      if (BIAS) {
        unsigned int word = bb[(4 * lg + i) * 4 + w];
        if ((word >> lr) & 1u) s0 += -1e9f;
        if ((word >> (16 + lr)) & 1u) s1 += -1e9f;
      }
      if (gk0 >= kend) s0 = -3.0e38f;
      if (gk0 + 16 >= kend) s1 = -3.0e38f;
      float rm = fmaxf(s0, s1);
#pragma unroll
      for (int off = 1; off < 16; off <<= 1) rm = fmaxf(rm, __shfl_xor(rm, off, 64));
      float mn = fmaxf(mreg[i], rm);
      float corr = __expf(mreg[i] - mn);
      mreg[i] = mn;
      float p0 = __expf(s0 - mn), p1 = __expf(s1 - mn);
      lreg[i] = lreg[i] * corr + p0 + p1;
      accO0[i] *= corr;
      accO1[i] *= corr;
      Pt[w * 576 + (4 * lg + i) * 36 + lr] = (short)f2bf(p0);
      Pt[w * 576 + (4 * lg + i) * 36 + 16 + lr] = (short)f2bf(p1);
    }
    s8v pf = ldfrag(&Pt[w * 576 + lr * 36 + 4 * lg]);
    s8v vf0 = ldfrag(&Vt[lr * 132 + w * 32 + 4 * lg]);
    s8v vf1 = ldfrag(&Vt[(16 + lr) * 132 + w * 32 + 4 * lg]);
    accO0 = __builtin_amdgcn_mfma_f32_16x16x32_bf16(pf, vf0, accO0, 0, 0, 0);
    accO1 = __builtin_amdgcn_mfma_f32_16x16x32_bf16(pf, vf1, accO1, 0, 0, 0);
    __syncthreads();
  }
#pragma unroll
  for (int i = 0; i < 4; ++i) {
    float lv = lreg[i];
#pragma unroll
    for (int off = 1; off < 16; off <<= 1) lv += __shfl_xor(lv, off, 64);
    if (lr == 0) { Msh[w][4 * lg + i] = mreg[i]; Lsh[w][4 * lg + i] = lv; }
  }
#pragma unroll
  for (int i = 0; i < 4; ++i) {
    Osh[w * 528 + (4 * lg + i) * 33 + lr] = accO0[i];
    Osh[w * 528 + (4 * lg + i) * 33 + 16 + lr] = accO1[i];
  }
  __syncthreads();
  float* part = SPLIT
      ? outp + ((size_t)((blockIdx.x * gridDim.y + blockIdx.y) * S + seg)) * RECSZ
      : nullptr;
  for (int o = t; o < 512; o += 256) {
    int qq = o >> 5, d = o & 31;
    float M = fmaxf(fmaxf(Msh[0][qq], Msh[1][qq]), fmaxf(Msh[2][qq], Msh[3][qq]));
    float lt = 0.f, Ov = 0.f;
#pragma unroll
    for (int w4 = 0; w4 < 4; ++w4) {
      float wt = __expf(Msh[w4][qq] - M);
      lt += wt * Lsh[w4][qq];
      Ov += wt * Osh[w4 * 528 + qq * 33 + d];
    }
    if (SPLIT) {
      if (d == 0) { part[qq] = M; part[16 + qq] = lt; }
      part[32 + qq * 32 + d] = Ov;
    } else if (q0 + qq < Q_) {
      outp[(size_t)(b * Q_ + q0 + qq) * D_ + h * HD_ + d] = Ov / lt;
    }
  }
}

// ---------------- split-K combine ----------------
__global__ __launch_bounds__(256) void attncomb_kernel(
    const float* __restrict__ part, float* __restrict__ out, int S, int nqt) {
  const int row = blockIdx.x;
  const int b = row / Q_, qq = row % Q_;
  const int t = threadIdx.x;
  const int h = t >> 5, d = t & 31;
  const int qt = qq >> 4, r = qq & 15;
  const float* base = part + ((size_t)((b * 8 + h) * nqt + qt) * S) * RECSZ;
  float M = -3.0e38f;
  for (int s = 0; s < S; ++s) M = fmaxf(M, base[(size_t)s * RECSZ + r]);
  float lt = 0.f, Ov = 0.f;
  for (int s = 0; s < S; ++s) {
    const float* rec = base + (size_t)s * RECSZ;
    float w = __expf(rec[r] - M);
    lt += w * rec[16 + r];
    Ov += w * rec[32 + r * 32 + d];
  }
  out[(size_t)row * D_ + h * HD_ + d] = Ov / lt;
}

// ---------------- threshold + pack bias bits from rbias ----------------
__global__ __launch_bounds__(256) void packbits_kernel(
    const float* __restrict__ r, unsigned int* __restrict__ bias, int P, int ldr) {
  __shared__ float red[256];
  __shared__ unsigned int bw[128];
  const int row = blockIdx.x;
  const int b = row / Q_, qq = row % Q_;
  const int t = threadIdx.x;
  const float* src = r + (size_t)b * Q_ * ldr + (size_t)qq * ldr;
  const int Pw = (P + 31) >> 5;
  float nign = 0.f;
  for (int p = t; p < P; p += 256)
    if (!(src[p] < 0.f)) nign += 1.f;
  float tot = block_sum(nign, red);
  bool fully = (tot == 0.f);
  for (int w = t; w < Pw; w += 256) bw[w] = 0u;
  __syncthreads();
  if (!fully) {
    for (int p = t; p < P; p += 256) {
      if (src[p] < 0.f) atomicOr(&bw[p >> 5], 1u << (p & 31));
    }
  }
  __syncthreads();
  unsigned int* dst = bias + (size_t)row * Pw;
  for (int w = t; w < Pw; w += 256) dst[w] = bw[w];
}

// ---------------- host dispatch ----------------
static inline void mg(hipStream_t st, int bm, int amode, int wmode, bool relu,
                      const void* A, const void* W, const float* bias, void* C,
                      int M, int N, int K, int Z,
                      long long Abs, long long Wbs, long long Cbs, int ldc) {
  dim3 g(N / 128, (M + bm - 1) / bm, Z);
  if (bm == 32) {
    if (relu)
      mgemm_kernel<32, 0, 0, true, 0><<<g, 256, 0, st>>>(A, W, bias, C, M, N, K, Abs, Wbs, Cbs, ldc, 0);
    else
      mgemm_kernel<32, 0, 0, false, 0><<<g, 256, 0, st>>>(A, W, bias, C, M, N, K, Abs, Wbs, Cbs, ldc, 0);
  } else {
    if (amode == 1)
      mgemm_kernel<64, 1, 0, false, 1><<<g, 256, 0, st>>>(A, W, bias, C, M, N, K, Abs, Wbs, Cbs, ldc, 0);
    else
      mgemm_kernel<64, 0, 0, false, 0><<<g, 256, 0, st>>>(A, W, bias, C, M, N, K, Abs, Wbs, Cbs, ldc, 0);
  }
}

extern "C" void kernel_launch(void* const* d_in, const int* in_sizes, int n_in,
                              void* d_out, int out_size, void* d_ws, size_t ws_size,
                              hipStream_t stream) {
  const float* mask_features = (const float*)d_in[0];
  const float* mem[3] = {(const float*)d_in[1], (const float*)d_in[2], (const float*)d_in[3]};
  const float* qf = (const float*)d_in[4];
  const float* qe = (const float*)d_in[5];
  const float* ca_wqkv = (const float*)d_in[6];
  const float* ca_bqkv = (const float*)d_in[7];
  const float* ca_wo = (const float*)d_in[8];
  const float* ca_bo = (const float*)d_in[9];
  const float* ca_ln_s = (const float*)d_in[10];
  const float* ca_ln_b = (const float*)d_in[11];
  const float* sa_wqkv = (const float*)d_in[12];
  const float* sa_bqkv = (const float*)d_in[13];
  const float* sa_wo = (const float*)d_in[14];
  const float* sa_bo = (const float*)d_in[15];
  const float* sa_ln_s = (const float*)d_in[16];
  const float* sa_ln_b = (const float*)d_in[17];
  const float* ffn_w1 = (const float*)d_in[18];
  const float* ffn_b1 = (const float*)d_in[19];
  const float* ffn_w2 = (const float*)d_in[20];
  const float* ffn_b2 = (const float*)d_in[21];
  const float* ffn_ln_s = (const float*)d_in[22];
  const float* ffn_ln_b = (const float*)d_in[23];
  const float* dec_ln_s = (const float*)d_in[24];
  const float* dec_ln_b = (const float*)d_in[25];
  const float* me_w1 = (const float*)d_in[26];
  const float* me_b1 = (const float*)d_in[27];
  const float* me_w2 = (const float*)d_in[28];
  const float* me_b2 = (const float*)d_in[29];
  const float* me_w3 = (const float*)d_in[30];
  const float* me_b3 = (const float*)d_in[31];
  const float* cls_w = (const float*)d_in[32];
  const float* cls_b = (const float*)d_in[33];

  float* out_logits = (float*)d_out;
  float* out_mask = (float*)d_out + (size_t)800 * C_;

  float* fws = (float*)d_ws;
  float* q      = fws; fws += (size_t)800 * D_;
  float* qh     = fws; fws += (size_t)800 * D_;
  float* attn_o = fws; fws += (size_t)800 * D_;
  float* tmp    = fws; fws += (size_t)800 * D_;
  float* nq     = fws; fws += (size_t)800 * D_;
  float* me3    = fws; fws += (size_t)800 * D_;
  float* kvbuf  = fws; fws += (size_t)B_ * PMAX_ * 256;    // bf16 [B][P][512]
  float* qkvbuf = fws; fws += (size_t)800 * 768;
  float* biasb  = fws; fws += (size_t)800 * 128;
  float* ffnh   = fws; fws += (size_t)B_ * Q_ * F_;
  float* part   = fws; fws += (size_t)64 * 7 * 3 * RECSZ;
  float* rmf0   = fws; fws += (size_t)B_ * 256 * 196;
  float* rmf1   = fws; fws += (size_t)B_ * 256 * 784;
  float* rmf2   = fws; fws += (size_t)B_ * 256 * 3136;
  float* rbias  = fws; fws += (size_t)B_ * Q_ * 3200;

  unsigned short* kvb = (unsigned short*)kvbuf;
  unsigned int* biasbits = (unsigned int*)biasb;

  short* sws = (short*)fws;
  short* W2ca  = sws; sws += (size_t)27 * 256 * 512;
  short* W2sa  = sws; sws += (size_t)27 * 256 * 512;
  short* W2cao = sws; sws += (size_t)9 * 256 * 512;
  short* W2sao = sws; sws += (size_t)9 * 256 * 512;
  short* W2f1  = sws; sws += (size_t)9 * 2048 * 512;
  short* W2f2  = sws; sws += (size_t)9 * 256 * 4096;
  short* W2me  = sws; sws += (size_t)3 * 256 * 512;
  short* mem2s = sws; sws += (size_t)B_ * 3136 * 512;
  short* mem1s = sws; sws += (size_t)B_ * 784 * 512;
  short* mem0s = sws; sws += (size_t)B_ * 196 * 512;
  short* memsp[3] = {mem0s, mem1s, mem2s};
  short* rmfs0 = sws; sws += (size_t)B_ * 256 * 512;
  short* rmfs1 = sws; sws += (size_t)B_ * 896 * 512;
  short* rmfs2 = sws; sws += (size_t)B_ * 3200 * 512;
  short* rmfs[3] = {rmfs0, rmfs1, rmfs2};

  tsplit_kernel<<<dim3(8, 8, 27), 256, 0, stream>>>(ca_wqkv, W2ca, 256, 256, 65536, 131072);
  tsplit_kernel<<<dim3(8, 8, 27), 256, 0, stream>>>(sa_wqkv, W2sa, 256, 256, 65536, 131072);
  tsplit_kernel<<<dim3(8, 8, 9), 256, 0, stream>>>(ca_wo, W2cao, 256, 256, 65536, 131072);
  tsplit_kernel<<<dim3(8, 8, 9), 256, 0, stream>>>(sa_wo, W2sao, 256, 256, 65536, 131072);
  tsplit_kernel<<<dim3(64, 8, 9), 256, 0, stream>>>(ffn_w1, W2f1, 256, 2048, 524288, 1048576);
  tsplit_kernel<<<dim3(8, 64, 9), 256, 0, stream>>>(ffn_w2, W2f2, 2048, 256, 524288, 1048576);
  tsplit_kernel<<<dim3(8, 8, 1), 256, 0, stream>>>(me_w1, W2me, 256, 256, 0, 0);
  tsplit_kernel<<<dim3(8, 8, 1), 256, 0, stream>>>(me_w2, W2me + 131072, 256, 256, 0, 0);
  tsplit_kernel<<<dim3(8, 8, 1), 256, 0, stream>>>(me_w3, W2me + 262144, 256, 256, 0, 0);
  tsplit_kernel<<<dim3(7, 8, 8), 256, 0, stream>>>(mem[0], mem0s, 256, 196, 256 * 196, 196 * 512);
  tsplit_kernel<<<dim3(25, 8, 8), 256, 0, stream>>>(mem[1], mem1s, 256, 784, 256 * 784, 784 * 512);
  tsplit_kernel<<<dim3(98, 8, 8), 256, 0, stream>>>(mem[2], mem2s, 256, 3136, 256 * 3136, 3136 * 512);

  // ---- resize mask_features once to 3 resolutions, then transpose-split (padded) ----
  resize3_kernel<<<2048, 256, 0, stream>>>(mask_features, rmf0, rmf1, rmf2);
  tsplitp_kernel<<<dim3(8, 8, 8), 256, 0, stream>>>(rmf0, rmfs0, 256, 196, 256,
                                                    256 * 196, 256 * 512);
  tsplitp_kernel<<<dim3(28, 8, 8), 256, 0, stream>>>(rmf1, rmfs1, 256, 784, 896,
                                                     256 * 784, 896 * 512);
  tsplitp_kernel<<<dim3(100, 8, 8), 256, 0, stream>>>(rmf2, rmfs2, 256, 3136, 3200,
                                                      256 * 3136, 3200 * 512);

  initq_kernel<<<800, 256, 0, stream>>>(qf, qe, q);

  const int Ps[3] = {196, 784, 3136};
  const int Ppad[3] = {256, 896, 3200};
  const int Ss[3] = {1, 2, 3};
  for (int i = 0; i < L_; ++i) {
    const int mi = i % 3, P = Ps[mi];
    const int Pw = (P + 31) >> 5;
    const int S = Ss[mi];
    const int ntiles = (P + KT_ - 1) / KT_;
    const int tps = (ntiles + S - 1) / S;
    // ---- cross-attention (biasbits prepared at end of previous layer) ----
    mg(stream, 32, 0, 0, false, q, W2ca + (size_t)(i * 3) * 131072, ca_bqkv + i * 768, qh,
       800, 256, 256, 1, 0, 0, 0, 256);
    mg(stream, 64, 1, 0, false, memsp[mi], W2ca + (size_t)(i * 3 + 1) * 131072,
       ca_bqkv + i * 768 + 256, kvb,
       P, 512, 256, B_, (long long)P * 512, 0, (long long)P * 512, 512);
    {
      dim3 ag(64, 7, S);
      if (S > 1) {
        if (i > 0)
          mattn_kernel<true, true, true><<<ag, 256, 0, stream>>>(
              qh, 256, kvb, 512, kvb + 256, 512, biasbits, part, P, Pw, tps, S);
        else
          mattn_kernel<false, true, true><<<ag, 256, 0, stream>>>(
              qh, 256, kvb, 512, kvb + 256, 512, nullptr, part, P, Pw, tps, S);
        attncomb_kernel<<<800, 256, 0, stream>>>(part, attn_o, S, 7);
      } else {
        if (i > 0)
          mattn_kernel<true, true, false><<<ag, 256, 0, stream>>>(
              qh, 256, kvb, 512, kvb + 256, 512, biasbits, attn_o, P, Pw, tps, S);
        else
          mattn_kernel<false, true, false><<<ag, 256, 0, stream>>>(
              qh, 256, kvb, 512, kvb + 256, 512, nullptr, attn_o, P, Pw, tps, S);
      }
    }
    mg(stream, 32, 0, 0, false, attn_o, W2cao + (size_t)i * 131072, ca_bo + i * 256, tmp,
       800, 256, 256, 1, 0, 0, 0, 256);
    ln_kernel<true><<<200, 256, 0, stream>>>(tmp, q, ca_ln_s + i * 256, ca_ln_b + i * 256, q, 800);
    // ---- self-attention ----
    mg(stream, 32, 0, 0, false, q, W2sa + (size_t)(i * 3) * 131072, sa_bqkv + i * 768, qkvbuf,
       800, 768, 256, 1, 0, 0, 0, 768);
    mattn_kernel<false, false, false><<<dim3(64, 7, 1), 256, 0, stream>>>(
        qkvbuf, 768, qkvbuf + 256, 768, qkvbuf + 512, 768, nullptr, attn_o, 100, 4, 1, 1);
    mg(stream, 32, 0, 0, false, attn_o, W2sao + (size_t)i * 131072, sa_bo + i * 256, tmp,
       800, 256, 256, 1, 0, 0, 0, 256);
    ln_kernel<true><<<200, 256, 0, stream>>>(tmp, q, sa_ln_s + i * 256, sa_ln_b + i * 256, q, 800);
    // ---- FFN ----
    mg(stream, 32, 0, 0, true, q, W2f1 + (size_t)i * 1048576, ffn_b1 + i * 2048, ffnh,
       800, 2048, 256, 1, 0, 0, 0, 2048);
    mg(stream, 32, 0, 0, false, ffnh, W2f2 + (size_t)i * 1048576, ffn_b2 + i * 256, tmp,
       800, 256, 2048, 1, 0, 0, 0, 256);
    ln_kernel<true><<<200, 256, 0, stream>>>(tmp, q, ffn_ln_s + i * 256, ffn_ln_b + i * 256, q, 800);
    // ---- fused mask head (dec_ln + me1 + me2 + me3) ----
    maskhead_kernel<<<50, 256, 0, stream>>>(q, dec_ln_s, dec_ln_b, W2me,
                                            me_b1, me_b2, me_b3, nq, me3);
    if (i < L_ - 1) {
      // ---- bias for NEXT layer: me3 @ resized-mask-features, then threshold+pack ----
      const int mn = (i + 1) % 3;
      const int Pn = Ps[mn], Pp = Ppad[mn];
      mgemm_kernel<32, 0, 0, false, 0><<<dim3(Pp / 128, 4, 8), 256, 0, stream>>>(
          me3, rmfs[mn], nullptr, rbias, 100, Pp, 256,
          (long long)100 * 256, (long long)Pp * 512, (long long)100 * Pp, Pp, 0);
      packbits_kernel<<<800, 256, 0, stream>>>(rbias, biasbits, Pn, Pp);
    } else {
      // ---- final layer: full-resolution pred_mask einsum (only once per call) ----
      mgemm_kernel<64, 0, 1, false, 0><<<dim3(2, 98, 8), 256, 0, stream>>>(
          me3, mask_features, nullptr, out_mask, 100, 12544, 256,
          (long long)100 * 256, (long long)256 * 12544, (long long)100 * 12544, 12544, 1);
    }
  }
  gemm32_kernel<<<dim3(3, 13, 1), 256, 0, stream>>>(nq, cls_w, cls_b, out_logits, 800, C_, 256);
}